// Round 1
// baseline (1014.015 us; speedup 1.0000x reference)
//
#include <hip/hip_runtime.h>

// Problem constants: D=2048, d=64, s=32, n=65536, K=d+s=96
// quad[s,col] = sum_{k<2080} theta[k,s] * phi[i_k,col]*phi[j_k,col]  (triu order)
// out[r,col]  = c[r] + sum_{k<96} Q[r,k] * z[k,col],  z = [phi; quad]

// ---------------- Kernel A: quad = theta.T @ psi(phi) ----------------
// grid (n/128, 2), block 128. blockIdx.y selects s-half (16 outputs/thread).
__global__ __launch_bounds__(128) void quad_kernel(
    const float* __restrict__ phi,
    const float* __restrict__ theta,
    float* __restrict__ quad,
    const int n)
{
    __shared__ float ph[64][128];   // 32 KiB: phi tile, [row][localcol]
    const int tid = threadIdx.x;
    const int colbase = blockIdx.x * 128;
    const int shalf = blockIdx.y;   // 0 or 1 — wave-uniform via blockIdx

    // stage 64x128 phi tile, coalesced
    #pragma unroll
    for (int t = 0; t < 64; ++t) {
        const int e = t * 128 + tid;
        const int i = e >> 7;
        const int cc = e & 127;
        ph[i][cc] = phi[(size_t)i * n + colbase + cc];
    }
    __syncthreads();

    const float* __restrict__ th = theta + shalf * 16;

    float acc[16];
    #pragma unroll
    for (int ss = 0; ss < 16; ++ss) acc[ss] = 0.f;

    const float* __restrict__ tk = th;   // walks theta rows (uniform -> s_load)
    for (int i = 0; i < 64; ++i) {
        const float pi = ph[i][tid];
        for (int j = i; j < 64; ++j) {
            const float psi = pi * ph[j][tid];
            #pragma unroll
            for (int ss = 0; ss < 16; ++ss)
                acc[ss] = fmaf(tk[ss], psi, acc[ss]);
            tk += 32;
        }
    }

    const int col = colbase + tid;
    #pragma unroll
    for (int ss = 0; ss < 16; ++ss)
        quad[(size_t)(shalf * 16 + ss) * n + col] = acc[ss];
}

// ---------------- Kernel B: out = c + Q @ [phi; quad] ----------------
// 64x64 tile, 256 threads, 4x4 microtile, K=96 fully staged (no K loop).
// grid (D/64, n/64): consecutive blocks share the Z tile (L2-hot).
__global__ __launch_bounds__(256) void out_kernel(
    const float* __restrict__ cvec,
    const float* __restrict__ Q,
    const float* __restrict__ phi,
    const float* __restrict__ quad,
    float* __restrict__ out,
    const int n)
{
    __shared__ float Qt[96 * 64];   // 24 KiB, [k][r]  (Q tile transposed)
    __shared__ float Zs[96 * 64];   // 24 KiB, [k][c]
    const int tid = threadIdx.x;
    const int rowbase = blockIdx.x * 64;
    const int colbase = blockIdx.y * 64;

    // stage Q tile transposed: thread (r = tid>>2, kg = (tid&3)*24) reads 24 k's
    {
        const int r = tid >> 2;            // 0..63
        const int kg = (tid & 3) * 24;     // 0,24,48,72
        const float* qp = Q + (size_t)(rowbase + r) * 96 + kg;
        #pragma unroll
        for (int t = 0; t < 6; ++t) {
            const float4 v = *(const float4*)(qp + t * 4);
            const int k0 = kg + t * 4;
            Qt[(k0 + 0) * 64 + r] = v.x;
            Qt[(k0 + 1) * 64 + r] = v.y;
            Qt[(k0 + 2) * 64 + r] = v.z;
            Qt[(k0 + 3) * 64 + r] = v.w;
        }
    }
    // stage Z tile: rows 0..63 = phi, 64..95 = quad (from workspace)
    #pragma unroll
    for (int t = 0; t < 6; ++t) {
        const int q = t * 256 + tid;       // quad index, 96*16 total
        const int k = q >> 4;              // 0..95
        const int c4 = (q & 15) * 4;       // 0..60
        const float* src = (k < 64) ? (phi + (size_t)k * n)
                                    : (quad + (size_t)(k - 64) * n);
        *(float4*)&Zs[k * 64 + c4] = *(const float4*)(src + colbase + c4);
    }
    __syncthreads();

    const int cg = tid & 15;
    const int rg = tid >> 4;
    const int c0 = cg * 4;
    const int r0 = rg * 4;

    float acc[16];
    #pragma unroll
    for (int t = 0; t < 16; ++t) acc[t] = 0.f;

    #pragma unroll 8
    for (int k = 0; k < 96; ++k) {
        const float4 a = *(const float4*)&Qt[k * 64 + r0];  // broadcast (4 quads/wave)
        const float4 b = *(const float4*)&Zs[k * 64 + c0];  // 2-way (free)
        acc[0]  = fmaf(a.x, b.x, acc[0]);
        acc[1]  = fmaf(a.x, b.y, acc[1]);
        acc[2]  = fmaf(a.x, b.z, acc[2]);
        acc[3]  = fmaf(a.x, b.w, acc[3]);
        acc[4]  = fmaf(a.y, b.x, acc[4]);
        acc[5]  = fmaf(a.y, b.y, acc[5]);
        acc[6]  = fmaf(a.y, b.z, acc[6]);
        acc[7]  = fmaf(a.y, b.w, acc[7]);
        acc[8]  = fmaf(a.z, b.x, acc[8]);
        acc[9]  = fmaf(a.z, b.y, acc[9]);
        acc[10] = fmaf(a.z, b.z, acc[10]);
        acc[11] = fmaf(a.z, b.w, acc[11]);
        acc[12] = fmaf(a.w, b.x, acc[12]);
        acc[13] = fmaf(a.w, b.y, acc[13]);
        acc[14] = fmaf(a.w, b.z, acc[14]);
        acc[15] = fmaf(a.w, b.w, acc[15]);
    }

    #pragma unroll
    for (int i = 0; i < 4; ++i) {
        const int row = rowbase + r0 + i;
        const float cv = cvec[row];
        float4 v;
        v.x = acc[i * 4 + 0] + cv;
        v.y = acc[i * 4 + 1] + cv;
        v.z = acc[i * 4 + 2] + cv;
        v.w = acc[i * 4 + 3] + cv;
        *(float4*)&out[(size_t)row * n + colbase + c0] = v;
    }
}

extern "C" void kernel_launch(void* const* d_in, const int* in_sizes, int n_in,
                              void* d_out, int out_size, void* d_ws, size_t ws_size,
                              hipStream_t stream) {
    const float* c     = (const float*)d_in[0];
    const float* Q     = (const float*)d_in[1];
    const float* phi   = (const float*)d_in[2];
    const float* theta = (const float*)d_in[3];
    float* out  = (float*)d_out;
    float* quad = (float*)d_ws;            // 32*n floats = 8 MiB scratch

    const int D = in_sizes[0];             // 2048
    const int n = in_sizes[2] / 64;        // 65536

    quad_kernel<<<dim3(n / 128, 2), 128, 0, stream>>>(phi, theta, quad, n);
    out_kernel<<<dim3(D / 64, n / 64), 256, 0, stream>>>(c, Q, phi, quad, out, n);
}

// Round 2
// 870.421 us; speedup vs baseline: 1.1650x; 1.1650x over previous
//
#include <hip/hip_runtime.h>

// D=2048, d=64, s=32, n=65536, K=d+s=96
// quad[s,c] = sum_{k<2080} theta[k,s]*phi[i_k,c]*phi[j_k,c]  (triu order)
// out[r,c]  = c[r] + sum_{k<96} Q[r,k]*z[k,c],  z=[phi;quad]
// Strategy: z transposed to [col][96] bf16 hi/lo in ws; Q to bf16 hi/lo;
// out GEMM via 16x16x32 bf16 MFMA with 3-product split (QhZh+QhZl+QlZh).

typedef short bf16x8 __attribute__((ext_vector_type(8)));
typedef float f32x4 __attribute__((ext_vector_type(4)));
typedef unsigned short u16;
typedef unsigned int u32;

__device__ inline u16 f2bf_rn(float x) {
    u32 u = __float_as_uint(x);
    return (u16)((u + 0x7FFFu + ((u >> 16) & 1u)) >> 16);
}
__device__ inline float bf2f(u16 h) { return __uint_as_float((u32)h << 16); }
__device__ inline void bsplit(float x, u16& h, u16& l) {
    h = f2bf_rn(x);
    l = f2bf_rn(x - bf2f(h));
}

__device__ inline void gload_lds16(const void* g, void* l) {
    __builtin_amdgcn_global_load_lds(
        (const __attribute__((address_space(1))) void*)g,
        (__attribute__((address_space(3))) void*)l,
        16, 0, 0);
}

// ---------------- qprep: Q fp32 -> Qh/Ql bf16 (same [row][96] layout) -------
__global__ __launch_bounds__(256) void qprep_kernel(
    const float* __restrict__ Q, u16* __restrict__ qh, u16* __restrict__ ql,
    const int total)
{
    const int e = blockIdx.x * 256 + threadIdx.x;
    if (e < total) {
        u16 h, l;
        bsplit(Q[e], h, l);
        qh[e] = h;
        ql[e] = l;
    }
}

// ---------------- quad: compute quad, emit zT[col][96] bf16 hi/lo ----------
// grid (n/128, 2), block 128. shalf=0 also emits the phi rows (k 0..63).
__global__ __launch_bounds__(128) void quad_kernel(
    const float* __restrict__ phi,
    const float* __restrict__ theta,
    u16* __restrict__ zh, u16* __restrict__ zl,
    const int n)
{
    __shared__ float ph[64][128];
    const int tid = threadIdx.x;
    const int colbase = blockIdx.x * 128;
    const int shalf = blockIdx.y;

    #pragma unroll
    for (int t = 0; t < 64; ++t) {
        const int e = t * 128 + tid;
        const int i = e >> 7;
        const int cc = e & 127;
        ph[i][cc] = phi[(size_t)i * n + colbase + cc];
    }
    __syncthreads();

    float acc[16];
    #pragma unroll
    for (int ss = 0; ss < 16; ++ss) acc[ss] = 0.f;

    const float* __restrict__ tk = theta + shalf * 16;
    for (int i = 0; i < 64; ++i) {
        const float pi = ph[i][tid];
        for (int j = i; j < 64; ++j) {
            const float psi = pi * ph[j][tid];
            #pragma unroll
            for (int ss = 0; ss < 16; ++ss)
                acc[ss] = fmaf(tk[ss], psi, acc[ss]);
            tk += 32;
        }
    }

    const int c = colbase + tid;
    const size_t rb = (size_t)c * 96;

    // quad part: k = 64 + shalf*16 + ss  -> 16 contiguous u16 per array
    {
        bf16x8 vh0, vh1, vl0, vl1;
        #pragma unroll
        for (int j = 0; j < 8; ++j) {
            u16 h, l;
            bsplit(acc[j], h, l);     vh0[j] = (short)h; vl0[j] = (short)l;
            bsplit(acc[8 + j], h, l); vh1[j] = (short)h; vl1[j] = (short)l;
        }
        const size_t base = rb + 64 + shalf * 16;
        *(bf16x8*)&zh[base] = vh0;
        *(bf16x8*)&zh[base + 8] = vh1;
        *(bf16x8*)&zl[base] = vl0;
        *(bf16x8*)&zl[base + 8] = vl1;
    }

    // phi part (only shalf==0): k = 0..63 from the LDS tile (transpose)
    if (shalf == 0) {
        #pragma unroll
        for (int ib = 0; ib < 64; ib += 8) {
            bf16x8 vh, vl;
            #pragma unroll
            for (int j = 0; j < 8; ++j) {
                u16 h, l;
                bsplit(ph[ib + j][tid], h, l);
                vh[j] = (short)h;
                vl[j] = (short)l;
            }
            *(bf16x8*)&zh[rb + ib] = vh;
            *(bf16x8*)&zl[rb + ib] = vl;
        }
    }
}

// ---------------- out GEMM: MFMA bf16 split-3 ------------------------------
// block 256 (4 waves), tile M=64 x N=128, K=96 staged once. LDS 72 KiB.
// u16 offsets: Qh 0(6144), Ql 6144, Zh 12288(12288), Zl 24576.
__global__ __launch_bounds__(256) void out_kernel(
    const float* __restrict__ cvec,
    const u16* __restrict__ qh, const u16* __restrict__ ql,
    const u16* __restrict__ zh, const u16* __restrict__ zl,
    float* __restrict__ out, const int n)
{
    __shared__ u16 lds[36864];   // 72 KiB
    const int tid = threadIdx.x;
    const int lane = tid & 63;
    const int wid = tid >> 6;
    const int rowbase = blockIdx.x * 64;
    const int colbase = blockIdx.y * 128;

    // stage 4 contiguous global regions; each call = 1 KiB per wave
    {
        const char* gq_h = (const char*)(qh + (size_t)rowbase * 96) + lane * 16;
        const char* gq_l = (const char*)(ql + (size_t)rowbase * 96) + lane * 16;
        const char* gz_h = (const char*)(zh + (size_t)colbase * 96) + lane * 16;
        const char* gz_l = (const char*)(zl + (size_t)colbase * 96) + lane * 16;
        char* lb = (char*)&lds[0];
        for (int jc = wid; jc < 12; jc += 4) {
            gload_lds16(gq_h + jc * 1024, lb + jc * 1024);
            gload_lds16(gq_l + jc * 1024, lb + 12288 + jc * 1024);
        }
        for (int jc = wid; jc < 24; jc += 4) {
            gload_lds16(gz_h + jc * 1024, lb + 24576 + jc * 1024);
            gload_lds16(gz_l + jc * 1024, lb + 49152 + jc * 1024);
        }
    }
    __syncthreads();

    f32x4 acc[4][2] = {};
    const int ar = lane & 15;     // frag row (A) / frag col (B)
    const int ag = lane >> 4;     // k subgroup; slot bijection shared by A & B
    const int wc0 = wid * 32;

    #pragma unroll
    for (int ks = 0; ks < 3; ++ks) {
        const int ko = ks * 32 + ag * 8;
        bf16x8 bh[2], bl[2];
        #pragma unroll
        for (int nf = 0; nf < 2; ++nf) {
            const int c = wc0 + nf * 16 + ar;
            bh[nf] = *(const bf16x8*)&lds[12288 + c * 96 + ko];
            bl[nf] = *(const bf16x8*)&lds[24576 + c * 96 + ko];
        }
        #pragma unroll
        for (int m = 0; m < 4; ++m) {
            const int r = m * 16 + ar;
            const bf16x8 ahf = *(const bf16x8*)&lds[r * 96 + ko];
            const bf16x8 alf = *(const bf16x8*)&lds[6144 + r * 96 + ko];
            #pragma unroll
            for (int nf = 0; nf < 2; ++nf) {
                acc[m][nf] = __builtin_amdgcn_mfma_f32_16x16x32_bf16(ahf, bh[nf], acc[m][nf], 0, 0, 0);
                acc[m][nf] = __builtin_amdgcn_mfma_f32_16x16x32_bf16(ahf, bl[nf], acc[m][nf], 0, 0, 0);
                acc[m][nf] = __builtin_amdgcn_mfma_f32_16x16x32_bf16(alf, bh[nf], acc[m][nf], 0, 0, 0);
            }
        }
    }

    // epilogue: D[row=(lane>>4)*4+reg][col=lane&15]  (HW-verified layout)
    const int r4 = (lane >> 4) * 4;
    #pragma unroll
    for (int m = 0; m < 4; ++m) {
        const int rb = rowbase + m * 16 + r4;
        #pragma unroll
        for (int j = 0; j < 4; ++j) {
            const float cv = cvec[rb + j];
            #pragma unroll
            for (int nf = 0; nf < 2; ++nf) {
                const int cc = colbase + wc0 + nf * 16 + (lane & 15);
                out[(size_t)(rb + j) * n + cc] = acc[m][nf][j] + cv;
            }
        }
    }
}

extern "C" void kernel_launch(void* const* d_in, const int* in_sizes, int n_in,
                              void* d_out, int out_size, void* d_ws, size_t ws_size,
                              hipStream_t stream) {
    const float* c     = (const float*)d_in[0];
    const float* Q     = (const float*)d_in[1];
    const float* phi   = (const float*)d_in[2];
    const float* theta = (const float*)d_in[3];
    float* out = (float*)d_out;

    const int D = in_sizes[0];         // 2048
    const int n = in_sizes[2] / 64;    // 65536

    // ws layout (bytes): zh [0, n*192) | zl | qh (D*192) | ql
    u16* zh = (u16*)d_ws;
    u16* zl = (u16*)((char*)d_ws + (size_t)n * 192);
    u16* qh = (u16*)((char*)d_ws + (size_t)n * 384);
    u16* ql = (u16*)((char*)d_ws + (size_t)n * 384 + (size_t)D * 192);

    qprep_kernel<<<(D * 96 + 255) / 256, 256, 0, stream>>>(Q, qh, ql, D * 96);
    quad_kernel<<<dim3(n / 128, 2), 128, 0, stream>>>(phi, theta, zh, zl, n);
    out_kernel<<<dim3(D / 64, n / 128), 256, 0, stream>>>(c, qh, ql, zh, zl, out, n);
}